// Round 9
// baseline (252.741 us; speedup 1.0000x reference)
//
#include <hip/hip_runtime.h>
#include <math.h>

#define TT 16384            // tokens
#define HD 4096             // hidden
#define NE 64               // experts
#define TM 32               // tokens per epilogue block
#define NBLK (TT / TM)      // 512 epilogue blocks
#define TAU 1e-5f           // near-tie fixup threshold (prob units)
// ---- gemm geometry ----
#define KSP 4               // split-K
#define HSP6 (HD / KSP)     // 1024 h per split
#define T6 64               // tokens per block
#define NTB6 (TT / T6)      // 256 token-blocks (x4 kz = 1024 blocks, 4/CU)
#define BK6 32              // h per staged tile
#define NKT6 (HSP6 / BK6)   // 32 k-iterations

typedef __attribute__((ext_vector_type(8))) short s8v;   // 8 x bf16
typedef __attribute__((ext_vector_type(4))) float f4v;   // MFMA acc

// ---- async global->LDS (fallback kernel only) ----
__device__ __forceinline__ void async16(const void* src, void* dst) {
  __builtin_amdgcn_global_load_lds(
      (const __attribute__((address_space(1))) void*)src,
      (__attribute__((address_space(3))) void*)dst, 16, 0, 0);
}

#define FMA4(A, HV, WV)                                       \
  A = fmaf((HV).x, (WV).x, A); A = fmaf((HV).y, (WV).y, A);   \
  A = fmaf((HV).z, (WV).z, A); A = fmaf((HV).w, (WV).w, A);

// RNE float->bf16 (bit trick; inputs are normal randoms, no NaN)
__device__ __forceinline__ unsigned short f2bf(float f) {
  unsigned int u = __float_as_uint(f);
  return (unsigned short)((u + 0x7FFFu + ((u >> 16) & 1u)) >> 16);
}
__device__ __forceinline__ float bf2f(unsigned short h) {
  return __uint_as_float(((unsigned int)h) << 16);
}

__device__ __forceinline__ void split8(float4 a, float4 b, s8v& hi, s8v& lo) {
  float v[8] = {a.x, a.y, a.z, a.w, b.x, b.y, b.z, b.w};
#pragma unroll
  for (int i = 0; i < 8; ++i) {
    unsigned short h = f2bf(v[i]);
    unsigned short l = f2bf(v[i] - bf2f(h));
    hi[i] = (short)h; lo[i] = (short)l;
  }
}

// =====================================================================
// Kernel 0: W fp32 -> bf16 hi/lo planes; also zeroes nFlag (replaces the
// graph-captured hipMemsetAsync node, which cost ~55 us per replay).
// =====================================================================
__global__ void wconv(const float* __restrict__ W,
                      unsigned short* __restrict__ WH,
                      unsigned short* __restrict__ WL,
                      int* __restrict__ nFlag) {
  if (blockIdx.x == 0 && threadIdx.x == 0) *nFlag = 0;
  const int i = blockIdx.x * 256 + threadIdx.x;   // 65536 float4 groups
  const float4 v = *(const float4*)(W + (size_t)i * 4);
  float x[4] = {v.x, v.y, v.z, v.w};
#pragma unroll
  for (int j = 0; j < 4; ++j) {
    unsigned short h = f2bf(x[j]);
    WH[(size_t)i * 4 + j] = h;
    WL[(size_t)i * 4 + j] = f2bf(x[j] - bf2f(h));
  }
}

// =====================================================================
// Kernel 1: gemm_v7 — bf16x3 MFMA split-K GEMM.
// Same geometry/numerics as R8's validated gemm_v6 (bitwise-identical
// MFMA inputs). Change: W B-fragments are per-lane global dwordx4 loads
// (coalesced 16 rows x 64B, L2-resident), prefetched 1 kt ahead into
// registers — no LDS for W, no async16, no per-kt HBM vmcnt drain.
// X: reg-staged fp32 -> split8 once/elem -> swizzled ds_write (2-buffer).
// =====================================================================
__launch_bounds__(256, 4)
__global__ void gemm_v7(const float* __restrict__ X,
                        const unsigned short* __restrict__ WH,
                        const unsigned short* __restrict__ WL,
                        float* __restrict__ part) {
  __shared__ __align__(16) unsigned short sXH[2][T6 * BK6];  // 4 KB each
  __shared__ __align__(16) unsigned short sXL[2][T6 * BK6];

  const int tid  = threadIdx.x;
  const int lane = tid & 63;
  const int w    = tid >> 6;
  const int tb   = blockIdx.x & (NTB6 - 1);
  const int kz   = blockIdx.x >> 8;          // NTB6 == 256
  const int t0   = tb * T6;
  const int h0   = kz * HSP6;

  // ---- X reg-staging source: thread (row xr, bf16-chunk xc = 8 h) ----
  const int xr = tid >> 2;                   // token row 0..63
  const int xc = tid & 3;                    // chunk 0..3
  const float* xsrc = X + (size_t)(t0 + xr) * HD + h0 + xc * 8;
  const int xwoff = xr * BK6 + ((xc ^ ((xr >> 1) & 3)) << 3);  // LDS elem off

  const int fr = lane & 15;
  const int fq = lane >> 4;

  // ---- W B-frag sources: lane (fr,fq), nf: expert row, 16B chunk ----
  // k = fq*8 + i  ->  ushort offset = eg*HD + h0 + kt*BK6 + fq*8
  const unsigned short* wsrc[2];
#pragma unroll
  for (int nf = 0; nf < 2; ++nf) {
    const int eg = (w & 1) * 32 + nf * 16 + fr;
    wsrc[nf] = (const unsigned short*)((size_t)eg * HD + h0 + fq * 8);
  }

  f4v acc[2][2];
#pragma unroll
  for (int mf = 0; mf < 2; ++mf)
#pragma unroll
    for (int nf = 0; nf < 2; ++nf) acc[mf][nf] = (f4v)(0.0f);

  // ---- prologue: X tile 0 + W frags for kt 0 ----
  float4 xa = *(const float4*)(xsrc);
  float4 xb = *(const float4*)(xsrc + 4);
  s8v bhC[2], blC[2];
#pragma unroll
  for (int nf = 0; nf < 2; ++nf) {
    bhC[nf] = *(const s8v*)(WH + (size_t)wsrc[nf]);
    blC[nf] = *(const s8v*)(WL + (size_t)wsrc[nf]);
  }
  {
    s8v hi, lo;
    split8(xa, xb, hi, lo);
    *(s8v*)&sXH[0][xwoff] = hi;
    *(s8v*)&sXL[0][xwoff] = lo;
  }
  __syncthreads();

  int buf = 0;
  for (int kt = 0; kt < NKT6; ++kt) {
    const bool more = (kt + 1 < NKT6);
    s8v bhN[2], blN[2];
    if (more) {
      const int o = (kt + 1) * BK6;
      xa = *(const float4*)(xsrc + o);
      xb = *(const float4*)(xsrc + o + 4);
#pragma unroll
      for (int nf = 0; nf < 2; ++nf) {
        bhN[nf] = *(const s8v*)(WH + (size_t)wsrc[nf] + o);
        blN[nf] = *(const s8v*)(WL + (size_t)wsrc[nf] + o);
      }
    }

    // ---- A-frags from LDS (4 ds_read_b128) + 12 MFMA ----
    s8v ah[2], al[2];
#pragma unroll
    for (int mf = 0; mf < 2; ++mf) {
      const int row = (w >> 1) * 32 + mf * 16 + fr;
      const int off = row * BK6 + ((fq ^ ((row >> 1) & 3)) << 3);
      ah[mf] = *(const s8v*)&sXH[buf][off];
      al[mf] = *(const s8v*)&sXL[buf][off];
    }
#pragma unroll
    for (int mf = 0; mf < 2; ++mf)
#pragma unroll
      for (int nf = 0; nf < 2; ++nf) {
        acc[mf][nf] = __builtin_amdgcn_mfma_f32_16x16x32_bf16(ah[mf], bhC[nf], acc[mf][nf], 0, 0, 0);
        acc[mf][nf] = __builtin_amdgcn_mfma_f32_16x16x32_bf16(ah[mf], blC[nf], acc[mf][nf], 0, 0, 0);
        acc[mf][nf] = __builtin_amdgcn_mfma_f32_16x16x32_bf16(al[mf], bhC[nf], acc[mf][nf], 0, 0, 0);
      }

    if (more) {
      s8v hi, lo;
      split8(xa, xb, hi, lo);
      *(s8v*)&sXH[buf ^ 1][xwoff] = hi;
      *(s8v*)&sXL[buf ^ 1][xwoff] = lo;
#pragma unroll
      for (int nf = 0; nf < 2; ++nf) { bhC[nf] = bhN[nf]; blC[nf] = blN[nf]; }
    }
    __syncthreads();
    buf ^= 1;
  }

  // ---- write partials: D col = fr (expert), row = fq*4+i (token) ----
#pragma unroll
  for (int mf = 0; mf < 2; ++mf)
#pragma unroll
    for (int nf = 0; nf < 2; ++nf) {
      const int e = (w & 1) * 32 + nf * 16 + fr;
#pragma unroll
      for (int i = 0; i < 4; ++i) {
        const int t = t0 + (w >> 1) * 32 + mf * 16 + fq * 4 + i;
        part[((size_t)kz * TT + t) * NE + e] = acc[mf][nf][i];
      }
    }
}

// =====================================================================
// Kernel 2: reduce_detect — sum 4 split-K partials -> logits, then
// near-tie detect (top-2/3 prob gap < TAU) with worklist compaction.
// =====================================================================
__global__ void reduce_detect(const float* __restrict__ part,
                              float* __restrict__ logits,
                              int* __restrict__ nFlag,
                              int* __restrict__ list) {
  const int t = blockIdx.x * 128 + threadIdx.x;
  float l[NE];
#pragma unroll
  for (int i = 0; i < 16; ++i) {
    float4 s = *(const float4*)(part + (size_t)t * NE + 4 * i);
#pragma unroll
    for (int k = 1; k < KSP; ++k) {
      const float4 v = *(const float4*)(part + ((size_t)k * TT + t) * NE + 4 * i);
      s.x += v.x; s.y += v.y; s.z += v.z; s.w += v.w;
    }
    *(float4*)(logits + (size_t)t * NE + 4 * i) = s;
    l[4 * i] = s.x; l[4 * i + 1] = s.y; l[4 * i + 2] = s.z; l[4 * i + 3] = s.w;
  }
  float m = -1e30f;
#pragma unroll
  for (int i = 0; i < NE; ++i) m = fmaxf(m, l[i]);
  float zs = 0.0f;
#pragma unroll
  for (int i = 0; i < NE; ++i) { l[i] = expf(l[i] - m); zs += l[i]; }
  float v1 = -1.0f, v2 = -1.0f, v3 = -1.0f;
#pragma unroll
  for (int i = 0; i < NE; ++i) {
    const float p = l[i];
    if (p > v1)      { v3 = v2; v2 = v1; v1 = p; }
    else if (p > v2) { v3 = v2; v2 = p; }
    else if (p > v3) { v3 = p; }
  }
  const float thr = TAU * zs;
  if (((v1 - v2) < thr) || ((v2 - v3) < thr)) {
    const int k = atomicAdd(nFlag, 1);
    list[k] = t;
  }
}

// =====================================================================
// Kernel 3: fixup — strided worklist, ~1 token/block. Per-token exact
// fp32 recompute (validated semantics), overwriting logits.
// =====================================================================
__global__ void fixup(const float* __restrict__ X,
                      const float* __restrict__ W,
                      const int* __restrict__ nFlag,
                      const int* __restrict__ list,
                      float* __restrict__ logits) {
  __shared__ float red[NE][4];
  const int tid = threadIdx.x;
  const int e   = tid >> 2;
  const int q   = tid & 3;
  const int n   = *nFlag;

  for (int idx = blockIdx.x; idx < n; idx += gridDim.x) {
    const int t = list[idx];
    const float* xr = X + (size_t)t * HD + q * 1024;
    const float* wr = W + (size_t)e * HD + q * 1024;
    float s = 0.0f;
    for (int h = 0; h < 1024; h += 4) {
      const float4 xv = *(const float4*)(xr + h);
      const float4 wv = *(const float4*)(wr + h);
      FMA4(s, xv, wv)
    }
    red[e][q] = s;
    __syncthreads();
    if (q == 0)
      logits[(size_t)t * NE + e] = (red[e][0] + red[e][1]) + (red[e][2] + red[e][3]);
    __syncthreads();
  }
}

// =====================================================================
// Kernel 4: epilogue — validated softmax/top-2/renorm/loss partials.
// =====================================================================
__global__ void router_epilogue(const float* __restrict__ logits,
                                float* __restrict__ out,
                                float* __restrict__ pP,
                                float* __restrict__ pC,
                                float* __restrict__ pZ) {
  __shared__ float psW[4][NE];
  __shared__ float cf[NE];
  __shared__ float zb[4];

  const int tid  = threadIdx.x;
  const int blk  = blockIdx.x;
  const int tx   = tid & 15;   // expert group (4 experts each)
  const int ty   = tid >> 4;   // token group (2 tokens each)
  const int wv   = tid >> 6;
  const int lane = tid & 63;

  if (tid < NE) cf[tid] = 0.0f;
  __syncthreads();

  float psum[4] = {0.f, 0.f, 0.f, 0.f};
  float zc = 0.0f;
#pragma unroll
  for (int i = 0; i < 2; ++i) {
    const int t = blk * TM + 2 * ty + i;
    const float4 lv = *(const float4*)(logits + (size_t)t * NE + 4 * tx);
    const float l0 = lv.x, l1 = lv.y, l2 = lv.z, l3 = lv.w;

    float m = fmaxf(fmaxf(l0, l1), fmaxf(l2, l3));
    m = fmaxf(m, __shfl_xor(m, 1));
    m = fmaxf(m, __shfl_xor(m, 2));
    m = fmaxf(m, __shfl_xor(m, 4));
    m = fmaxf(m, __shfl_xor(m, 8));
    const float e0 = expf(l0 - m), e1 = expf(l1 - m);
    const float e2 = expf(l2 - m), e3 = expf(l3 - m);
    float zs = (e0 + e1) + (e2 + e3);
    zs += __shfl_xor(zs, 1);
    zs += __shfl_xor(zs, 2);
    zs += __shfl_xor(zs, 4);
    zs += __shfl_xor(zs, 8);
    const float p0 = e0 / zs, p1 = e1 / zs, p2 = e2 / zs, p3 = e3 / zs;
    psum[0] += p0; psum[1] += p1; psum[2] += p2; psum[3] += p3;

    // local top-2 (ascending index => ties keep lower)
    float v1 = p0, v2 = p1; int i1 = 4 * tx, i2 = 4 * tx + 1;
    if (p1 > p0) { v1 = p1; i1 = 4 * tx + 1; v2 = p0; i2 = 4 * tx; }
    if (p2 > v1) { v2 = v1; i2 = i1; v1 = p2; i1 = 4 * tx + 2; }
    else if (p2 > v2) { v2 = p2; i2 = 4 * tx + 2; }
    if (p3 > v1) { v2 = v1; i2 = i1; v1 = p3; i1 = 4 * tx + 3; }
    else if (p3 > v2) { v2 = p3; i2 = 4 * tx + 3; }

    // butterfly merge across the 16 lanes of this token
#pragma unroll
    for (int s = 1; s <= 8; s <<= 1) {
      const float ov1 = __shfl_xor(v1, s); const int oi1 = __shfl_xor(i1, s);
      const float ov2 = __shfl_xor(v2, s); const int oi2 = __shfl_xor(i2, s);
      const bool o1 = (ov1 > v1) || (ov1 == v1 && oi1 < i1);
      if (o1) {
        const bool o2 = (ov2 > v1) || (ov2 == v1 && oi2 < i1);
        v2 = o2 ? ov2 : v1; i2 = o2 ? oi2 : i1;
        v1 = ov1; i1 = oi1;
      } else {
        const bool o2 = (ov1 > v2) || (ov1 == v2 && oi1 < i2);
        v2 = o2 ? ov1 : v2; i2 = o2 ? oi1 : i2;
      }
    }

    const float lz = m + logf(zs);
    if (tx == 0) {
      const float den = v1 + v2 + 1e-9f;
      out[2 * t]     = v1 / den;
      out[2 * t + 1] = v2 / den;
      out[2 * TT + 2 * t]     = (float)i1;
      out[2 * TT + 2 * t + 1] = (float)i2;
      atomicAdd(&cf[i1], 1.0f);
      atomicAdd(&cf[i2], 1.0f);
      zc += lz * lz;
    }
  }

#pragma unroll
  for (int j = 0; j < 4; ++j) {
    psum[j] += __shfl_xor(psum[j], 16);
    psum[j] += __shfl_xor(psum[j], 32);
  }
  if (lane < 16) {
#pragma unroll
    for (int j = 0; j < 4; ++j) psW[wv][4 * lane + j] = psum[j];
  }
  float z = zc;
#pragma unroll
  for (int s = 1; s <= 32; s <<= 1) z += __shfl_xor(z, s);
  if (lane == 0) zb[wv] = z;
  __syncthreads();

  if (tid < NE) {
    pP[blk * NE + tid] = psW[0][tid] + psW[1][tid] + psW[2][tid] + psW[3][tid];
    pC[blk * NE + tid] = cf[tid];
  }
  if (tid == 0) pZ[blk] = zb[0] + zb[1] + zb[2] + zb[3];
}

__global__ void router_final(const float* __restrict__ pP,
                             const float* __restrict__ pC,
                             const float* __restrict__ pZ,
                             float* __restrict__ out) {
  const int e = threadIdx.x;  // 64 threads = 1 wave
  float sP = 0.f, sC = 0.f;
  for (int b = 0; b < NBLK; ++b) {
    sP += pP[b * NE + e];
    sC += pC[b * NE + e];
  }
  const float f = sC * (1.0f / (TT * 2.0f));
  const float P = sP * (1.0f / (float)TT);
  out[4 * TT + 2 + e] = f;
  float term = f * P;
#pragma unroll
  for (int s = 1; s <= 32; s <<= 1) term += __shfl_xor(term, s);
  float zs = 0.f;
  for (int b = e; b < NBLK; b += NE) zs += pZ[b];
#pragma unroll
  for (int s = 1; s <= 32; s <<= 1) zs += __shfl_xor(zs, s);
  if (e == 0) {
    out[4 * TT]     = 0.01f * ((float)NE * term);
    out[4 * TT + 1] = 0.001f * (zs / (float)TT);
  }
}

// =====================================================================
// Fallback (validated round-1 fused kernel) for tiny ws_size.
// =====================================================================
__device__ __forceinline__ void async_copy16f(const float* src, float* dst) {
  async16((const void*)src, (void*)dst);
}

__launch_bounds__(256, 2)
__global__ void router_fused(const float* __restrict__ X,
                             const float* __restrict__ W,
                             float* __restrict__ out,
                             float* __restrict__ pP,
                             float* __restrict__ pC,
                             float* __restrict__ pZ) {
  __shared__ __align__(16) float sH[2][TM * 64];
  __shared__ __align__(16) float sW[2][NE * 64];
  __shared__ float psW[4][NE];
  __shared__ float cf[NE];
  __shared__ float zb[4];

  const int tid  = threadIdx.x;
  const int blk  = blockIdx.x;
  const int tx   = tid & 15;
  const int ty   = tid >> 4;
  const int wv   = tid >> 6;
  const int lane = tid & 63;

  if (tid < NE) cf[tid] = 0.0f;

  const int xoff = (tid & 15) << 4;
  const float* srcH[2];
  const float* srcW[4];
#pragma unroll
  for (int p = 0; p < 2; ++p) {
    const int r = ty + p * 16;
    const int sw = ((r >> 1) & 7) << 4;
    srcH[p] = X + (size_t)(blk * TM + r) * HD + ((xoff ^ sw) >> 2);
  }
#pragma unroll
  for (int p = 0; p < 4; ++p) {
    const int e = ty + p * 16;
    const int sw = ((e >> 2) & 7) << 4;
    srcW[p] = W + (size_t)e * HD + ((xoff ^ sw) >> 2);
  }

  auto stage = [&](int b, int kt) {
    const int o = kt * 64;
    float* dH = &sH[b][wv * 256];
    async_copy16f(srcH[0] + o, dH);
    async_copy16f(srcH[1] + o, dH + 1024);
    float* dW = &sW[b][wv * 256];
    async_copy16f(srcW[0] + o, dW);
    async_copy16f(srcW[1] + o, dW + 1024);
    async_copy16f(srcW[2] + o, dW + 2048);
    async_copy16f(srcW[3] + o, dW + 3072);
  };

  float acc[2][4] = {{0.f, 0.f, 0.f, 0.f}, {0.f, 0.f, 0.f, 0.f}};
  const int Hswz = (ty & 7) << 4;
  const int Wswz = (tx & 7) << 4;

  auto compute = [&](int b) {
    const char* hb = (const char*)(&sH[b][0]) + (ty << 9);
    const char* wb = (const char*)(&sW[b][0]) + (tx << 10);
#pragma unroll
    for (int h4 = 0; h4 < 16; ++h4) {
      const int oH = (h4 << 4) ^ Hswz;
      const int oW = (h4 << 4) ^ Wswz;
      const float4 h0 = *(const float4*)(hb + oH);
      const float4 h1 = *(const float4*)(hb + oH + 256);
      const float4 w0 = *(const float4*)(wb + oW);
      const float4 w1 = *(const float4*)(wb + oW + 256);
      const float4 w2 = *(const float4*)(wb + oW + 512);
      const float4 w3 = *(const float4*)(wb + oW + 768);
      FMA4(acc[0][0], h0, w0) FMA4(acc[0][1], h0, w1)
      FMA4(acc[0][2], h0, w2) FMA4(acc[0][3], h0, w3)
      FMA4(acc[1][0], h1, w0) FMA4(acc[1][1], h1, w1)
      FMA4(acc[1][2], h1, w2) FMA4(acc[1][3], h1, w3)
    }
  };

  int buf = 0;
  stage(0, 0);
  __syncthreads();
  for (int kt = 0; kt < 64; ++kt) {
    if (kt + 1 < 64) stage(buf ^ 1, kt + 1);
    compute(buf);
    __syncthreads();
    buf ^= 1;
  }

  float psum[4] = {0.f, 0.f, 0.f, 0.f};
  float zc = 0.0f;
#pragma unroll
  for (int i = 0; i < 2; ++i) {
    const float l0 = acc[i][0], l1 = acc[i][1], l2 = acc[i][2], l3 = acc[i][3];
    float m = fmaxf(fmaxf(l0, l1), fmaxf(l2, l3));
    m = fmaxf(m, __shfl_xor(m, 1));
    m = fmaxf(m, __shfl_xor(m, 2));
    m = fmaxf(m, __shfl_xor(m, 4));
    m = fmaxf(m, __shfl_xor(m, 8));
    const float e0 = expf(l0 - m), e1 = expf(l1 - m);
    const float e2 = expf(l2 - m), e3 = expf(l3 - m);
    float zs = (e0 + e1) + (e2 + e3);
    zs += __shfl_xor(zs, 1);
    zs += __shfl_xor(zs, 2);
    zs += __shfl_xor(zs, 4);
    zs += __shfl_xor(zs, 8);
    const float p0 = e0 / zs, p1 = e1 / zs, p2 = e2 / zs, p3 = e3 / zs;
    psum[0] += p0; psum[1] += p1; psum[2] += p2; psum[3] += p3;

    float v1 = p0, v2 = p1; int i1 = 4 * tx, i2 = 4 * tx + 1;
    if (p1 > p0) { v1 = p1; i1 = 4 * tx + 1; v2 = p0; i2 = 4 * tx; }
    if (p2 > v1) { v2 = v1; i2 = i1; v1 = p2; i1 = 4 * tx + 2; }
    else if (p2 > v2) { v2 = p2; i2 = 4 * tx + 2; }
    if (p3 > v1) { v2 = v1; i2 = i1; v1 = p3; i1 = 4 * tx + 3; }
    else if (p3 > v2) { v2 = p3; i2 = 4 * tx + 3; }

#pragma unroll
    for (int s = 1; s <= 8; s <<= 1) {
      const float ov1 = __shfl_xor(v1, s); const int oi1 = __shfl_xor(i1, s);
      const float ov2 = __shfl_xor(v2, s); const int oi2 = __shfl_xor(i2, s);
      const bool o1 = (ov1 > v1) || (ov1 == v1 && oi1 < i1);
      if (o1) {
        const bool o2 = (ov2 > v1) || (ov2 == v1 && oi2 < i1);
        v2 = o2 ? ov2 : v1; i2 = o2 ? oi2 : i1;
        v1 = ov1; i1 = oi1;
      } else {
        const bool o2 = (ov1 > v2) || (ov1 == v2 && oi1 < i2);
        v2 = o2 ? ov1 : v2; i2 = o2 ? oi1 : i2;
      }
    }

    const float lz = m + logf(zs);
    if (tx == 0) {
      const int t = blk * TM + 2 * ty + i;
      const float den = v1 + v2 + 1e-9f;
      out[2 * t]     = v1 / den;
      out[2 * t + 1] = v2 / den;
      out[2 * TT + 2 * t]     = (float)i1;
      out[2 * TT + 2 * t + 1] = (float)i2;
      atomicAdd(&cf[i1], 1.0f);
      atomicAdd(&cf[i2], 1.0f);
      zc += lz * lz;
    }
  }

#pragma unroll
  for (int j = 0; j < 4; ++j) {
    psum[j] += __shfl_xor(psum[j], 16);
    psum[j] += __shfl_xor(psum[j], 32);
  }
  if (lane < 16) {
#pragma unroll
    for (int j = 0; j < 4; ++j) psW[wv][4 * lane + j] = psum[j];
  }
  float z = zc;
#pragma unroll
  for (int s = 1; s <= 32; s <<= 1) z += __shfl_xor(z, s);
  if (lane == 0) zb[wv] = z;
  __syncthreads();

  if (tid < NE) {
    pP[blk * NE + tid] = psW[0][tid] + psW[1][tid] + psW[2][tid] + psW[3][tid];
    pC[blk * NE + tid] = cf[tid];
  }
  if (tid == 0) pZ[blk] = zb[0] + zb[1] + zb[2] + zb[3];
}

extern "C" void kernel_launch(void* const* d_in, const int* in_sizes, int n_in,
                              void* d_out, int out_size, void* d_ws, size_t ws_size,
                              hipStream_t stream) {
  const float* X = (const float*)d_in[0];   // [16384, 4096] f32
  const float* W = (const float*)d_in[1];   // [64, 4096] f32
  float* out = (float*)d_out;
  (void)in_sizes; (void)n_in; (void)out_size;

  // ws: WH, WL (ushort 64*4096 each), part f32[4][TT][NE], logits f32[TT][NE],
  //     pP, pC, pZ, nFlag, list
  const size_t WHALF = (size_t)NE * HD;                 // ushorts per plane
  const size_t PART6 = (size_t)KSP * TT * NE;           // floats
  const size_t LOGF  = (size_t)TT * NE;                 // floats
  const size_t AUXF  = (size_t)NBLK * NE * 2 + NBLK;
  const size_t NEEDB = WHALF * 2 * sizeof(unsigned short) +
                       (PART6 + LOGF + AUXF) * sizeof(float) +
                       (1 + TT) * sizeof(int);

  if (ws_size >= NEEDB) {
    unsigned short* WH = (unsigned short*)d_ws;
    unsigned short* WL = WH + WHALF;
    float* part   = (float*)(WL + WHALF);
    float* logits = part + PART6;
    float* pP = logits + LOGF;
    float* pC = pP + NBLK * NE;
    float* pZ = pC + NBLK * NE;
    int* nFlag = (int*)(pZ + NBLK);
    int* list  = nFlag + 1;
    wconv<<<dim3(256), dim3(256), 0, stream>>>(W, WH, WL, nFlag);
    gemm_v7<<<dim3(NTB6 * KSP), dim3(256), 0, stream>>>(X, WH, WL, part);
    reduce_detect<<<dim3(TT / 128), dim3(128), 0, stream>>>(part, logits, nFlag, list);
    fixup<<<dim3(512), dim3(256), 0, stream>>>(X, W, nFlag, list, logits);
    router_epilogue<<<dim3(NBLK), dim3(256), 0, stream>>>(logits, out, pP, pC, pZ);
    router_final<<<dim3(1), dim3(NE), 0, stream>>>(pP, pC, pZ, out);
  } else {
    float* pP = (float*)d_ws;
    float* pC = pP + NBLK * NE;
    float* pZ = pC + NBLK * NE;
    router_fused<<<dim3(NBLK), dim3(256), 0, stream>>>(X, W, out, pP, pC, pZ);
    router_final<<<dim3(1), dim3(NE), 0, stream>>>(pP, pC, pZ, out);
  }
}